// Round 1
// baseline (778.119 us; speedup 1.0000x reference)
//
#include <hip/hip_runtime.h>
#include <hip/hip_bf16.h>

typedef __attribute__((ext_vector_type(8))) short short8;
typedef __attribute__((ext_vector_type(4))) float f32x4;

#define DEVINL __device__ __forceinline__

constexpr int Bc = 4, Sc = 2048, Dc = 2048, Hc = 16, DHc = 128;
constexpr float SCALE = 0.08838834764831845f;  // 1/sqrt(128)

DEVINL short f2bf(float f) {
  unsigned u = __builtin_bit_cast(unsigned, f);
  u = (u + 0x7fffu + ((u >> 16) & 1u)) >> 16;
  return (short)u;
}
DEVINL unsigned pack2(float a, float b) {
  return (unsigned)(unsigned short)f2bf(a) | ((unsigned)(unsigned short)f2bf(b) << 16);
}

// ---------------- weight transpose + fp32->bf16:  wt[n][k] = w[k][n] -------
__global__ __launch_bounds__(256) void transpose_w_kernel(
    const float* __restrict__ w0, const float* __restrict__ w1,
    const float* __restrict__ w2, const float* __restrict__ w3,
    short* __restrict__ wt) {
  __shared__ float tile[32][33];
  const float* w = (blockIdx.z == 0) ? w0 : (blockIdx.z == 1) ? w1
                   : (blockIdx.z == 2) ? w2 : w3;
  short* out = wt + (size_t)blockIdx.z * Dc * Dc;
  int k0 = blockIdx.x * 32, n0 = blockIdx.y * 32;
  int t = threadIdx.x;
#pragma unroll
  for (int p = 0; p < 4; ++p) {
    int idx = p * 256 + t;
    int kr = idx >> 5, nc = idx & 31;
    tile[kr][nc] = w[(size_t)(k0 + kr) * Dc + n0 + nc];
  }
  __syncthreads();
#pragma unroll
  for (int p = 0; p < 4; ++p) {
    int idx = p * 256 + t;
    int nr = idx >> 5, kc = idx & 31;
    out[(size_t)(n0 + nr) * Dc + k0 + kc] = f2bf(tile[kc][nr]);
  }
}

// ---------------- GEMM: C[M,N] = A[M,K] @ Wt[N,K]^T + bias ----------------
// OUT_MODE: 0 = bf16 [M,N], 1 = f32 [M,N], 2 = bf16 V-transposed [B,H,DH,S]
template <bool A_IS_F32, int OUT_MODE>
__global__ __launch_bounds__(256, 2) void gemm_kernel(
    const void* __restrict__ Aptr, const short* __restrict__ Wt,
    const float* __restrict__ bias, void* __restrict__ Cptr) {
  constexpr int BM = 128, BN = 128, BK = 32, PAD = 8;
  __shared__ short As[BM][BK + PAD];
  __shared__ short Bs[BN][BK + PAD];
  const int tid = threadIdx.x;
  const int lane = tid & 63, wid = tid >> 6;
  const int wm = wid >> 1, wn = wid & 1;
  const int m0 = blockIdx.y * BM, n0 = blockIdx.x * BN;
  const int lr = lane & 15, lk = (lane >> 4) * 8;

  f32x4 acc[4][4] = {};

  for (int k0 = 0; k0 < Dc; k0 += BK) {
    if (A_IS_F32) {
      const float* A = (const float*)Aptr;
      int c4 = (tid & 7) * 4;
      int rbase = tid >> 3;
#pragma unroll
      for (int p = 0; p < 4; ++p) {
        int r = rbase + p * 32;
        const f32x4 v = *(const f32x4*)&A[(size_t)(m0 + r) * Dc + k0 + c4];
        uint2 w2;
        w2.x = pack2(v[0], v[1]);
        w2.y = pack2(v[2], v[3]);
        *(uint2*)&As[r][c4] = w2;
      }
    } else {
      const short* A = (const short*)Aptr;
      int c8 = (tid & 3) * 8;
      int rbase = tid >> 2;
#pragma unroll
      for (int p = 0; p < 2; ++p) {
        int r = rbase + p * 64;
        *(short8*)&As[r][c8] = *(const short8*)&A[(size_t)(m0 + r) * Dc + k0 + c8];
      }
    }
    {
      int c8 = (tid & 3) * 8;
      int rbase = tid >> 2;
#pragma unroll
      for (int p = 0; p < 2; ++p) {
        int r = rbase + p * 64;
        *(short8*)&Bs[r][c8] = *(const short8*)&Wt[(size_t)(n0 + r) * Dc + k0 + c8];
      }
    }
    __syncthreads();
    short8 af[4], bf[4];
#pragma unroll
    for (int i = 0; i < 4; ++i) af[i] = *(const short8*)&As[wm * 64 + i * 16 + lr][lk];
#pragma unroll
    for (int j = 0; j < 4; ++j) bf[j] = *(const short8*)&Bs[wn * 64 + j * 16 + lr][lk];
#pragma unroll
    for (int i = 0; i < 4; ++i)
#pragma unroll
      for (int j = 0; j < 4; ++j)
        acc[i][j] = __builtin_amdgcn_mfma_f32_16x16x32_bf16(af[i], bf[j], acc[i][j], 0, 0, 0);
    __syncthreads();
  }

  const int rowl = (lane >> 4) * 4;
#pragma unroll
  for (int i = 0; i < 4; ++i) {
#pragma unroll
    for (int j = 0; j < 4; ++j) {
      int gcol = n0 + wn * 64 + j * 16 + lr;
      float bv = bias[gcol];
#pragma unroll
      for (int r = 0; r < 4; ++r) {
        int grow = m0 + wm * 64 + i * 16 + rowl + r;
        float v = acc[i][j][r] + bv;
        if (OUT_MODE == 1) {
          ((float*)Cptr)[(size_t)grow * Dc + gcol] = v;
        } else if (OUT_MODE == 0) {
          ((short*)Cptr)[(size_t)grow * Dc + gcol] = f2bf(v);
        } else {
          int b4 = grow >> 11, ss = grow & (Sc - 1);
          int hh = gcol >> 7, dh = gcol & (DHc - 1);
          ((short*)Cptr)[((((size_t)(b4 * Hc + hh) * DHc) + dh) << 11) + ss] = f2bf(v);
        }
      }
    }
  }
}

// ---------------- flash attention (causal) --------------------------------
// qp,kp: bf16 [B,S,D]; vt: bf16 [B,H,DH,S]; attn out: bf16 [B,S,D]
__global__ __launch_bounds__(256, 2) void attn_kernel(
    const short* __restrict__ qp, const short* __restrict__ kp,
    const short* __restrict__ vt, short* __restrict__ attn) {
  constexpr int QB = 64, KB = 64, PAD = 8;
  __shared__ short Ks[KB][DHc + PAD];   // 64 x 136
  __shared__ short Vs[DHc][KB + PAD];   // 128 x 72
  __shared__ short Ps[4][16][KB + PAD]; // per-wave P tile
  const int tid = threadIdx.x, lane = tid & 63, wid = tid >> 6;
  const int qb = blockIdx.x * QB;
  const int h = blockIdx.y, b = blockIdx.z;
  const int lr = lane & 15, lk = (lane >> 4) * 8;
  const int rowl = (lane >> 4) * 4;
  const size_t headq = ((size_t)b * Sc) * Dc + (size_t)h * DHc;

  const int qrow0 = qb + wid * 16;
  short8 qf[4];
#pragma unroll
  for (int c = 0; c < 4; ++c)
    qf[c] = *(const short8*)&qp[headq + (size_t)(qrow0 + lr) * Dc + c * 32 + lk];

  f32x4 o[8] = {};
  float mrun[4], lrun[4];
#pragma unroll
  for (int r = 0; r < 4; ++r) { mrun[r] = -1e30f; lrun[r] = 0.f; }

  const size_t vbase = (((size_t)b * Hc + h) * DHc) << 11;
  const int ntiles = qb / KB + 1;
  for (int t = 0; t < ntiles; ++t) {
    const int kvb = t * KB;
#pragma unroll
    for (int p = 0; p < 4; ++p) {
      int idx = p * 256 + tid;
      int r = idx >> 4, c8 = (idx & 15) * 8;
      *(short8*)&Ks[r][c8] = *(const short8*)&kp[headq + (size_t)(kvb + r) * Dc + c8];
    }
#pragma unroll
    for (int p = 0; p < 4; ++p) {
      int idx = p * 256 + tid;
      int r = idx >> 3, c8 = (idx & 7) * 8;
      *(short8*)&Vs[r][c8] = *(const short8*)&vt[vbase + ((size_t)r << 11) + kvb + c8];
    }
    __syncthreads();

    f32x4 sc[4];
#pragma unroll
    for (int nb = 0; nb < 4; ++nb) {
      f32x4 s = {};
#pragma unroll
      for (int c = 0; c < 4; ++c) {
        short8 kf = *(const short8*)&Ks[nb * 16 + lr][c * 32 + lk];
        s = __builtin_amdgcn_mfma_f32_16x16x32_bf16(qf[c], kf, s, 0, 0, 0);
      }
      sc[nb] = s;
    }

    float mt[4];
#pragma unroll
    for (int r = 0; r < 4; ++r) mt[r] = -1e30f;
#pragma unroll
    for (int nb = 0; nb < 4; ++nb) {
      int kv = kvb + nb * 16 + lr;
#pragma unroll
      for (int r = 0; r < 4; ++r) {
        int qr = qrow0 + rowl + r;
        float v = sc[nb][r] * SCALE;
        v = (kv > qr) ? -1e30f : v;
        sc[nb][r] = v;
        mt[r] = fmaxf(mt[r], v);
      }
    }
#pragma unroll
    for (int off = 1; off < 16; off <<= 1)
#pragma unroll
      for (int r = 0; r < 4; ++r) mt[r] = fmaxf(mt[r], __shfl_xor(mt[r], off));

    float alpha[4], lsum[4];
#pragma unroll
    for (int r = 0; r < 4; ++r) {
      float mnew = fmaxf(mrun[r], mt[r]);
      alpha[r] = __expf(mrun[r] - mnew);
      mrun[r] = mnew;
      lsum[r] = 0.f;
    }
#pragma unroll
    for (int nb = 0; nb < 4; ++nb) {
#pragma unroll
      for (int r = 0; r < 4; ++r) {
        float p = __expf(sc[nb][r] - mrun[r]);
        lsum[r] += p;
        Ps[wid][rowl + r][nb * 16 + lr] = f2bf(p);
      }
    }
#pragma unroll
    for (int off = 1; off < 16; off <<= 1)
#pragma unroll
      for (int r = 0; r < 4; ++r) lsum[r] += __shfl_xor(lsum[r], off);
#pragma unroll
    for (int r = 0; r < 4; ++r) lrun[r] = lrun[r] * alpha[r] + lsum[r];
#pragma unroll
    for (int f = 0; f < 8; ++f)
#pragma unroll
      for (int r = 0; r < 4; ++r) o[f][r] *= alpha[r];

    asm volatile("s_waitcnt lgkmcnt(0)" ::: "memory");
#pragma unroll
    for (int kc = 0; kc < 2; ++kc) {
      short8 pf = *(const short8*)&Ps[wid][lr][kc * 32 + lk];
#pragma unroll
      for (int nb = 0; nb < 8; ++nb) {
        short8 vf = *(const short8*)&Vs[nb * 16 + lr][kc * 32 + lk];
        o[nb] = __builtin_amdgcn_mfma_f32_16x16x32_bf16(pf, vf, o[nb], 0, 0, 0);
      }
    }
    __syncthreads();
  }

#pragma unroll
  for (int f = 0; f < 8; ++f) {
#pragma unroll
    for (int r = 0; r < 4; ++r) {
      float v = o[f][r] / lrun[r];
      attn[headq + (size_t)(qrow0 + rowl + r) * Dc + f * 16 + lr] = f2bf(v);
    }
  }
}

// ---------------------------------------------------------------------------
extern "C" void kernel_launch(void* const* d_in, const int* in_sizes, int n_in,
                              void* d_out, int out_size, void* d_ws, size_t ws_size,
                              hipStream_t stream) {
  const float* Q = (const float*)d_in[0];
  const float* K = (const float*)d_in[1];
  const float* V = (const float*)d_in[2];
  // d_in[3] = mask (causal tril, structural — unused)
  const float* wq = (const float*)d_in[4];
  const float* bq = (const float*)d_in[5];
  const float* wk = (const float*)d_in[6];
  const float* bk = (const float*)d_in[7];
  const float* wv = (const float*)d_in[8];
  const float* bv = (const float*)d_in[9];
  const float* wo = (const float*)d_in[10];
  const float* bo = (const float*)d_in[11];

  char* ws = (char*)d_ws;
  const size_t WSZ = (size_t)Dc * Dc;   // weight elems
  const size_t XSZ = (size_t)Bc * Sc * Dc;
  short* WT = (short*)ws;                                   // 4 weights bf16^T
  short* QP = (short*)(ws + 4 * WSZ * 2);
  short* KP = (short*)(ws + 4 * WSZ * 2 + XSZ * 2);
  short* VT = (short*)(ws + 4 * WSZ * 2 + 2 * XSZ * 2);
  short* AT = (short*)(ws + 4 * WSZ * 2 + 3 * XSZ * 2);
  // total: 8*WSZ + 8*XSZ bytes = 32 MiB + 128 MiB = 160 MiB

  transpose_w_kernel<<<dim3(Dc / 32, Dc / 32, 4), 256, 0, stream>>>(wq, wk, wv, wo, WT);

  dim3 gg(Dc / 128, (Bc * Sc) / 128);  // (16, 64)
  gemm_kernel<true, 0><<<gg, 256, 0, stream>>>(Q, WT, bq, QP);
  gemm_kernel<true, 0><<<gg, 256, 0, stream>>>(K, WT + WSZ, bk, KP);
  gemm_kernel<true, 2><<<gg, 256, 0, stream>>>(V, WT + 2 * WSZ, bv, VT);

  attn_kernel<<<dim3(Sc / 64, Hc, Bc), 256, 0, stream>>>(QP, KP, VT, AT);

  gemm_kernel<false, 1><<<gg, 256, 0, stream>>>(AT, WT + 3 * WSZ, bo, (float*)d_out);
}